// Round 3
// baseline (94.674 us; speedup 1.0000x reference)
//
#include <hip/hip_runtime.h>
#include <hip/hip_fp16.h>

typedef __attribute__((ext_vector_type(8))) _Float16 half8;
typedef __attribute__((ext_vector_type(4))) float f32x4;

union U2H2 { unsigned int u; __half2 h; };

static __device__ __forceinline__ unsigned int pack2h(float a, float b) {
    U2H2 c; c.h = __floats2half2_rn(a, b); return c.u;
}
static __device__ __forceinline__ __half2 u_as_h2(unsigned int u) {
    U2H2 c; c.u = u; return c.h;
}

// Kernel A: Wrh[k][o][c] = half(W[o, c*25+k]); k in [0,26), slice 25 zeroed (pad)
__global__ void prep_w(const float* __restrict__ W, unsigned short* __restrict__ Wrh) {
    int i = blockIdx.x * 256 + threadIdx.x;  // 26*2048 = 53248
    if (i >= 26 * 2048) return;
    int c = i & 31, o = (i >> 5) & 63, k = i >> 11;
    float v = (k < 25) ? W[o * 800 + c * 25 + k] : 0.f;
    __half h = __float2half(v);
    Wrh[i] = *reinterpret_cast<unsigned short*>(&h);
}

// Kernel B: transpose x (B,C,N) fp32 -> xth (B,N,32) fp16 (64B rows, gather-friendly)
__global__ __launch_bounds__(256) void transpose_x(const float* __restrict__ x,
                                                   unsigned short* __restrict__ xth, int N) {
    __shared__ float t[32][65];
    int b = blockIdx.y, n0 = blockIdx.x * 64, tid = threadIdx.x;
#pragma unroll
    for (int i = 0; i < 8; ++i) {
        int e = tid + 256 * i;
        int c = e >> 6, nl = e & 63, n = n0 + nl;
        t[c][nl] = (n < N) ? x[(size_t)(b * 32 + c) * N + n] : 0.f;
    }
    __syncthreads();
    int nl = tid >> 2, cg = tid & 3, n = n0 + nl;
    if (n < N) {
        uint4 p;
        p.x = pack2h(t[cg * 8 + 0][nl], t[cg * 8 + 1][nl]);
        p.y = pack2h(t[cg * 8 + 2][nl], t[cg * 8 + 3][nl]);
        p.z = pack2h(t[cg * 8 + 4][nl], t[cg * 8 + 5][nl]);
        p.w = pack2h(t[cg * 8 + 6][nl], t[cg * 8 + 7][nl]);
        *reinterpret_cast<uint4*>(xth + ((size_t)(b * N + n) * 32 + cg * 8)) = p;
    }
}

// Kernel C: fused gather + einsum + MFMA GEMM + bias
__global__ __launch_bounds__(256) void fused_main(
    const unsigned short* __restrict__ xth,  // [2][N][32] fp16
    const unsigned short* __restrict__ Wrh,  // [26][64][32] fp16
    const float* __restrict__ bias,          // [64]
    const int* __restrict__ nidx,            // [N][25][3]
    const float* __restrict__ nw,            // [N][25][3]
    float* __restrict__ out,                 // [2][64][N] fp32
    int N)
{
    __shared__ unsigned int idxw[26 * 96];               // j | (half(w)<<16), [k][nl][t]
    __shared__ __align__(16) unsigned char sA[2][4096];  // two swizzled k-slices, 64 rows x 64B

    const int tid = threadIdx.x;
    const int n0 = blockIdx.x * 32;

    // ---- preload all 25 k-slices of (idx, half(w)); slice 25 = zeros ----
#pragma unroll
    for (int it = 0; it < 10; ++it) {
        int e = tid + 256 * it;
        if (e < 2400) {
            int nl = e / 75;
            int rem = e - nl * 75;
            int n = n0 + nl;
            unsigned int u = 0;
            if (n < N) {
                int j = nidx[(size_t)n0 * 75 + e];
                __half hw = __float2half(nw[(size_t)n0 * 75 + e]);
                u = (unsigned int)j |
                    ((unsigned int)*reinterpret_cast<unsigned short*>(&hw) << 16);
            }
            int kk = rem / 3, t = rem - kk * 3;
            idxw[(kk * 32 + nl) * 3 + t] = u;
        }
    }
    if (tid < 96) idxw[2400 + tid] = 0u;
    __syncthreads();

    const int row = tid >> 2;   // 0..63 = b*32 + nl (this thread's gather row)
    const int l4  = tid & 3;    // 16B slice within the 64B row
    const int b0  = row >> 5;
    const int nl0 = row & 31;
    const unsigned short* xb = xth + (size_t)b0 * N * 32;

    const int l = tid & 63, wv = tid >> 6, c16 = l & 15, g = l >> 4;

    // conflict-free swizzle within each 16-row x 64B subtile: granule ^= (r&3)^((r>>2)&3)
    const int r16w = row & 15;
    const int wr_off = row * 64 + ((l4 ^ (r16w & 3) ^ ((r16w >> 2) & 3)) << 4);
    const int rd_off = (16 * wv + c16) * 64 + ((g ^ (c16 & 3) ^ ((c16 >> 2) & 3)) << 4);

    unsigned int rw[2][3];
    uint4 rg[2][3];
    uint4 rB[2][4];

    auto issue_gather = [&](int kp) {
#pragma unroll
        for (int ks = 0; ks < 2; ++ks) {
            int kk = kp * 2 + ks;
            const unsigned int* ip = &idxw[(kk * 32 + nl0) * 3];
#pragma unroll
            for (int t = 0; t < 3; ++t) {
                unsigned int u = ip[t];
                rw[ks][t] = u;
                rg[ks][t] = *reinterpret_cast<const uint4*>(
                    xb + ((size_t)(u & 0xffffu) * 32 + l4 * 8));
            }
        }
    };
    auto issue_B = [&](int kp) {
#pragma unroll
        for (int ks = 0; ks < 2; ++ks) {
            int kk = kp * 2 + ks;
#pragma unroll
            for (int ot = 0; ot < 4; ++ot)
                rB[ks][ot] = *reinterpret_cast<const uint4*>(
                    Wrh + kk * 2048 + (ot * 16 + c16) * 32 + g * 8);
        }
    };

    f32x4 acc[4];
#pragma unroll
    for (int ot = 0; ot < 4; ++ot) acc[ot] = (f32x4){0.f, 0.f, 0.f, 0.f};

    issue_gather(0);
    issue_B(0);

    for (int kp = 0; kp < 13; ++kp) {
        // ---- phase 1: weighted gather -> fp16 -> swizzled LDS A slices ----
#pragma unroll
        for (int ks = 0; ks < 2; ++ks) {
            __half2 w0 = u_as_h2(__builtin_amdgcn_perm(rw[ks][0], rw[ks][0], 0x03020302u));
            __half2 w1 = u_as_h2(__builtin_amdgcn_perm(rw[ks][1], rw[ks][1], 0x03020302u));
            __half2 w2 = u_as_h2(__builtin_amdgcn_perm(rw[ks][2], rw[ks][2], 0x03020302u));
            uint4 v0 = rg[ks][0], v1 = rg[ks][1], v2 = rg[ks][2];
            uint4 p;
            U2H2 c;
            c.h = __hfma2(u_as_h2(v0.x), w0, __hfma2(u_as_h2(v1.x), w1, __hmul2(u_as_h2(v2.x), w2)));
            p.x = c.u;
            c.h = __hfma2(u_as_h2(v0.y), w0, __hfma2(u_as_h2(v1.y), w1, __hmul2(u_as_h2(v2.y), w2)));
            p.y = c.u;
            c.h = __hfma2(u_as_h2(v0.z), w0, __hfma2(u_as_h2(v1.z), w1, __hmul2(u_as_h2(v2.z), w2)));
            p.z = c.u;
            c.h = __hfma2(u_as_h2(v0.w), w0, __hfma2(u_as_h2(v1.w), w1, __hmul2(u_as_h2(v2.w), w2)));
            p.w = c.u;
            *reinterpret_cast<uint4*>(&sA[ks][wr_off]) = p;
        }
        if (kp < 12) issue_gather(kp + 1);  // rg/rw consumed above -> safe to refill
        __syncthreads();

        // ---- phase 2: MFMA (A from LDS, B from prefetched regs) ----
#pragma unroll
        for (int ks = 0; ks < 2; ++ks) {
            half8 af = *reinterpret_cast<const half8*>(&sA[ks][rd_off]);
#pragma unroll
            for (int ot = 0; ot < 4; ++ot) {
                half8 bf = __builtin_bit_cast(half8, rB[ks][ot]);
                acc[ot] = __builtin_amdgcn_mfma_f32_16x16x32_f16(af, bf, acc[ot], 0, 0, 0);
            }
        }
        if (kp < 12) issue_B(kp + 1);  // rB consumed above -> safe to refill
        __syncthreads();               // protect sA before next phase-1 overwrite
    }

    // ---- epilogue: bias + store (D: col=lane&15 -> o, row=4*(lane>>4)+i) ----
#pragma unroll
    for (int ot = 0; ot < 4; ++ot) {
        int o = ot * 16 + c16;
        float bv = bias[o];
#pragma unroll
        for (int i = 0; i < 4; ++i) {
            int mrow = 16 * wv + 4 * g + i;
            int b = mrow >> 5, nl = mrow & 31;
            int n = n0 + nl;
            if (n < N) out[(size_t)(b * 64 + o) * N + n] = acc[ot][i] + bv;
        }
    }
}

extern "C" void kernel_launch(void* const* d_in, const int* in_sizes, int n_in,
                              void* d_out, int out_size, void* d_ws, size_t ws_size,
                              hipStream_t stream) {
    const float* x    = (const float*)d_in[0];   // (2,32,N)
    const float* nw   = (const float*)d_in[1];   // (N,25,3)
    const float* W    = (const float*)d_in[2];   // (64,800)
    const float* bias = (const float*)d_in[3];   // (64,)
    const int*   nidx = (const int*)d_in[4];     // (N,25,3)
    float* out = (float*)d_out;

    int N = in_sizes[0] / 64;  // B*C = 64

    unsigned short* xth = (unsigned short*)d_ws;        // 2*N*32 fp16
    unsigned short* Wrh = xth + (size_t)2 * N * 32;     // 26*2048 fp16

    prep_w<<<(26 * 2048 + 255) / 256, 256, 0, stream>>>(W, Wrh);

    dim3 tg((N + 63) / 64, 2);
    transpose_x<<<tg, 256, 0, stream>>>(x, xth, N);

    fused_main<<<(N + 31) / 32, 256, 0, stream>>>(xth, Wrh, bias, nidx, nw, out, N);
}

// Round 4
// 65.342 us; speedup vs baseline: 1.4489x; 1.4489x over previous
//
#include <hip/hip_runtime.h>
#include <hip/hip_fp16.h>

typedef __attribute__((ext_vector_type(8))) _Float16 half8;
typedef __attribute__((ext_vector_type(4))) float f32x4;

union U2H2 { unsigned int u; __half2 h; };

static __device__ __forceinline__ unsigned int pack2h(float a, float b) {
    U2H2 c; c.h = __floats2half2_rn(a, b); return c.u;
}
static __device__ __forceinline__ __half2 u_as_h2(unsigned int u) {
    U2H2 c; c.u = u; return c.h;
}

// swizzle: slot' = slot ^ s(row), s(row) = (row&3)^((row>>2)&3)
#define SWZ(row, slot) ((slot) ^ ((row) & 3) ^ (((row) >> 2) & 3))

// fence LDS + barrier WITHOUT draining vmcnt (keeps prefetched loads in flight)
#define LDS_BARRIER()                                                \
    do {                                                             \
        asm volatile("s_waitcnt lgkmcnt(0)" ::: "memory");           \
        __builtin_amdgcn_s_barrier();                                \
        __builtin_amdgcn_sched_barrier(0);                           \
    } while (0)

// Kernel A: Wrh[k][o][c] = half(W[o, c*25+k]), k in [0,25)
__global__ void prep_w(const float* __restrict__ W, unsigned short* __restrict__ Wrh) {
    int i = blockIdx.x * 256 + threadIdx.x;  // 25*2048 = 51200
    if (i >= 25 * 2048) return;
    int c = i & 31, o = (i >> 5) & 63, k = i >> 11;
    __half h = __float2half(W[o * 800 + c * 25 + k]);
    Wrh[i] = *reinterpret_cast<unsigned short*>(&h);
}

// Kernel B: x (B,C,N) fp32 -> xth [N][2][32] fp16 (128B per n: both b halves adjacent)
__global__ __launch_bounds__(256) void transpose_x(const float* __restrict__ x,
                                                   unsigned short* __restrict__ xth, int N) {
    __shared__ float t[2][32][65];
    int n0 = blockIdx.x * 64, tid = threadIdx.x;
#pragma unroll
    for (int i = 0; i < 16; ++i) {
        int e = tid + 256 * i;           // [2][32][64]
        int b = e >> 11, c = (e >> 6) & 31, nl = e & 63;
        int n = n0 + nl;
        t[b][c][nl] = (n < N) ? x[(size_t)(b * 32 + c) * N + n] : 0.f;
    }
    __syncthreads();
    int nl = tid >> 2, q = tid & 3, n = n0 + nl;
    if (n < N) {
#pragma unroll
        for (int b = 0; b < 2; ++b) {
            uint4 p;
            p.x = pack2h(t[b][q * 8 + 0][nl], t[b][q * 8 + 1][nl]);
            p.y = pack2h(t[b][q * 8 + 2][nl], t[b][q * 8 + 3][nl]);
            p.z = pack2h(t[b][q * 8 + 4][nl], t[b][q * 8 + 5][nl]);
            p.w = pack2h(t[b][q * 8 + 6][nl], t[b][q * 8 + 7][nl]);
            *reinterpret_cast<uint4*>(xth + ((size_t)n * 64 + b * 32 + q * 8)) = p;
        }
    }
}

// Kernel C: fused gather + einsum + MFMA GEMM + bias
__global__ __launch_bounds__(256) void fused_main(
    const unsigned short* __restrict__ xth,  // [N][2][32] fp16
    const unsigned short* __restrict__ Wrh,  // [25][64][32] fp16
    const float* __restrict__ bias,          // [64]
    const int* __restrict__ nidx,            // [N][25][3]
    const float* __restrict__ nw,            // [N][25][3]
    float* __restrict__ out,                 // [2][64][N] fp32
    int N)
{
    __shared__ unsigned int idxw[25 * 96];                  // j | (half(w)<<16), [k][nl][t]
    __shared__ __align__(16) unsigned char sA[2][4096];     // double-buffered A slice
    __shared__ __align__(16) unsigned char sB[2][4096];     // double-buffered B slice

    const int tid = threadIdx.x;
    const int n0 = blockIdx.x * 32;

    // ---- preload all 25 k-slices of (idx, half(w)) ----
#pragma unroll
    for (int it = 0; it < 10; ++it) {
        int e = tid + 256 * it;
        if (e < 2400) {
            int nl = e / 75;
            int rem = e - nl * 75;
            int n = n0 + nl;
            unsigned int u = 0;
            if (n < N) {
                int j = nidx[(size_t)n0 * 75 + e];
                __half hw = __float2half(nw[(size_t)n0 * 75 + e]);
                u = (unsigned int)j |
                    ((unsigned int)*reinterpret_cast<unsigned short*>(&hw) << 16);
            }
            int kk = rem / 3, t = rem - kk * 3;
            idxw[(kk * 32 + nl) * 3 + t] = u;
        }
    }
    __syncthreads();

    const int row = tid >> 2;      // 0..63 = b*32+nl (gather row this thread owns)
    const int l4  = tid & 3;       // 16B slice within 64B
    const int b0  = row >> 5;
    const int nl0 = row & 31;

    const int wr_off = row * 64 + (SWZ(row, l4) << 4);   // sA write
    const int sb_off = wr_off;                           // sB write (o=row, same map)

    const int l = tid & 63, wv = tid >> 6, c16 = l & 15, g = l >> 4;
    const int arow = 16 * wv + c16;
    const int rd_a = arow * 64 + (SWZ(arow, g) << 4);

    unsigned int ru[2][3];
    uint4 rg[2][3];
    uint4 rB;

    auto issue_g = [&](int kk, int buf) {
        const unsigned int* ip = &idxw[(kk * 32 + nl0) * 3];
#pragma unroll
        for (int t = 0; t < 3; ++t) {
            unsigned int u = ip[t];
            if (buf == 0) ru[0][t] = u; else ru[1][t] = u;
            uint4 v = *reinterpret_cast<const uint4*>(
                xth + ((size_t)(u & 0xffffu) * 64 + b0 * 32 + l4 * 8));
            if (buf == 0) rg[0][t] = v; else rg[1][t] = v;
        }
    };

    f32x4 acc[4];
#pragma unroll
    for (int ot = 0; ot < 4; ++ot) acc[ot] = (f32x4){0.f, 0.f, 0.f, 0.f};

    // prologue: B(0), g(0), g(1)  (issue order matters for counted waits)
    rB = *reinterpret_cast<const uint4*>(Wrh + tid * 8);
    issue_g(0, 0);
    issue_g(1, 1);

#pragma unroll 2
    for (int k = 0; k < 25; ++k) {
        const int buf = k & 1;

        // ---- phase 1: consume rB -> sB; refill B(k+1) ----
        *reinterpret_cast<uint4*>(&sB[buf][sb_off]) = rB;
        {
            int kB = (k + 1 < 25) ? k + 1 : 24;
            rB = *reinterpret_cast<const uint4*>(Wrh + kB * 2048 + tid * 8);
        }

        // ---- consume gathers -> weighted fp16 sum -> sA; refill g(k+2) ----
        {
            unsigned int u0, u1, u2;
            uint4 v0, v1, v2;
            if (buf == 0) { u0 = ru[0][0]; u1 = ru[0][1]; u2 = ru[0][2];
                            v0 = rg[0][0]; v1 = rg[0][1]; v2 = rg[0][2]; }
            else          { u0 = ru[1][0]; u1 = ru[1][1]; u2 = ru[1][2];
                            v0 = rg[1][0]; v1 = rg[1][1]; v2 = rg[1][2]; }
            __half2 w0 = u_as_h2(__builtin_amdgcn_perm(u0, u0, 0x03020302u));
            __half2 w1 = u_as_h2(__builtin_amdgcn_perm(u1, u1, 0x03020302u));
            __half2 w2 = u_as_h2(__builtin_amdgcn_perm(u2, u2, 0x03020302u));
            uint4 p; U2H2 c;
            c.h = __hfma2(u_as_h2(v0.x), w0, __hfma2(u_as_h2(v1.x), w1, __hmul2(u_as_h2(v2.x), w2)));
            p.x = c.u;
            c.h = __hfma2(u_as_h2(v0.y), w0, __hfma2(u_as_h2(v1.y), w1, __hmul2(u_as_h2(v2.y), w2)));
            p.y = c.u;
            c.h = __hfma2(u_as_h2(v0.z), w0, __hfma2(u_as_h2(v1.z), w1, __hmul2(u_as_h2(v2.z), w2)));
            p.z = c.u;
            c.h = __hfma2(u_as_h2(v0.w), w0, __hfma2(u_as_h2(v1.w), w1, __hmul2(u_as_h2(v2.w), w2)));
            p.w = c.u;
            *reinterpret_cast<uint4*>(&sA[buf][wr_off]) = p;
        }
        {
            int kg = (k + 2 < 25) ? k + 2 : 24;
            issue_g(kg, buf);  // refill the buffer just consumed
        }

        // ---- single barrier: LDS visible, vmem prefetch stays in flight ----
        LDS_BARRIER();

        // ---- phase 2: MFMA from LDS (buf) ----
        {
            half8 af = *reinterpret_cast<const half8*>(&sA[buf][rd_a]);
#pragma unroll
            for (int ot = 0; ot < 4; ++ot) {
                int orow = ot * 16 + c16;
                half8 bf = *reinterpret_cast<const half8*>(
                    &sB[buf][orow * 64 + (SWZ(orow, g) << 4)]);
                acc[ot] = __builtin_amdgcn_mfma_f32_16x16x32_f16(af, bf, acc[ot], 0, 0, 0);
            }
        }
    }

    // ---- epilogue: bias + store (D: col=lane&15 -> o, row=4*(lane>>4)+i) ----
#pragma unroll
    for (int ot = 0; ot < 4; ++ot) {
        int o = ot * 16 + c16;
        float bv = bias[o];
#pragma unroll
        for (int i = 0; i < 4; ++i) {
            int mrow = 16 * wv + 4 * g + i;
            int b = mrow >> 5, nl = mrow & 31;
            int n = n0 + nl;
            if (n < N) out[(size_t)(b * 64 + o) * N + n] = acc[ot][i] + bv;
        }
    }
}

extern "C" void kernel_launch(void* const* d_in, const int* in_sizes, int n_in,
                              void* d_out, int out_size, void* d_ws, size_t ws_size,
                              hipStream_t stream) {
    const float* x    = (const float*)d_in[0];   // (2,32,N)
    const float* nw   = (const float*)d_in[1];   // (N,25,3)
    const float* W    = (const float*)d_in[2];   // (64,800)
    const float* bias = (const float*)d_in[3];   // (64,)
    const int*   nidx = (const int*)d_in[4];     // (N,25,3)
    float* out = (float*)d_out;

    int N = in_sizes[0] / 64;  // B*C = 64

    unsigned short* xth = (unsigned short*)d_ws;      // [N][2][32] fp16
    unsigned short* Wrh = xth + (size_t)N * 64;       // [25][64][32] fp16

    prep_w<<<(25 * 2048 + 255) / 256, 256, 0, stream>>>(W, Wrh);

    transpose_x<<<(N + 63) / 64, 256, 0, stream>>>(x, xth, N);

    fused_main<<<(N + 31) / 32, 256, 0, stream>>>(xth, Wrh, bias, nidx, nw, out, N);
}